// Round 13
// baseline (214.384 us; speedup 1.0000x reference)
//
#include <hip/hip_runtime.h>

typedef float f32x4 __attribute__((ext_vector_type(4)));
typedef _Float16 h16;
typedef h16 half8 __attribute__((ext_vector_type(8)));

__device__ __forceinline__ float fast_tanh(float x) {
    float e = __expf(2.0f * x);
    return fmaf(-2.0f, __builtin_amdgcn_rcpf(e + 1.0f), 1.0f);
}
__device__ __forceinline__ half8 cvt8(float4 u0, float4 u1) {
    return (half8){(h16)u0.x,(h16)u0.y,(h16)u0.z,(h16)u0.w,
                   (h16)u1.x,(h16)u1.y,(h16)u1.z,(h16)u1.w};
}

#define S2IMGH 1576   // s2 halves per image: [196 pos + 1 pad][8 ch]

// ============================ K1: C1 via Toeplitz MFMA, row-split ============================
// grid = 2 * B/8. blockIdx: gb = bx>>1 (8-img group), ph = bx&1 (row half).
// ph0: conv rows cr 0..7 (pooled ip 0..3 per half); ph1: cr 8..13 (ip 4..6).
// All x rows preloaded to registers before the loop (no mid-loop global latency).
#define C1_IMG 8

template<int BASE, int NITER>
__device__ __forceinline__ void c1_phase(
    const float* __restrict__ xg, const half8 (&bf)[3][5], const float (&bias)[3],
    h16* __restrict__ s2l, int lane, int wv, int nloc, int q4)
{
    half8 rw[NITER + 4];
    #pragma unroll
    for (int r = 0; r < NITER + 4; ++r)
        rw[r] = cvt8(*(const float4*)(xg + (BASE + r) * 32),
                     *(const float4*)(xg + (BASE + r) * 32 + 4));

    float t0[3][4];
    #pragma unroll
    for (int cc = 0; cc < NITER; ++cc) {
        const int cr = BASE + cc;
        f32x4 acc[3];
        #pragma unroll
        for (int t = 0; t < 3; ++t) acc[t] = (f32x4){0.f, 0.f, 0.f, 0.f};
        #pragma unroll
        for (int ks = 0; ks < 5; ++ks) {
            #pragma unroll
            for (int t = 0; t < 3; ++t)
                acc[t] = __builtin_amdgcn_mfma_f32_16x16x32_f16(rw[cc + ks], bf[t][ks], acc[t], 0, 0, 0);
        }
        if ((cr & 1) == 0) {
            #pragma unroll
            for (int t = 0; t < 3; ++t)
                #pragma unroll
                for (int r = 0; r < 4; ++r)
                    t0[t][r] = fast_tanh(acc[t][r] + bias[t]);
        } else {
            #pragma unroll
            for (int t = 0; t < 3; ++t) {
                const int tile = 3 * wv + t;
                const int jp   = (((tile & 1) << 4) + nloc) >> 1;
                const int map  = tile >> 1;
                #pragma unroll
                for (int r = 0; r < 4; ++r) {
                    float s = t0[t][r] + fast_tanh(acc[t][r] + bias[t]);
                    float o = 0.25f * (s + __shfl_xor(s, 1));
                    const int m = q4 * 4 + r;                 // C/D row = m
                    const int img = m >> 1, mh = m & 1;
                    const int ip  = (cr >> 1) + 7 * mh;
                    if (!(lane & 1) && jp < 14)
                        s2l[img * S2IMGH + (ip * 14 + jp) * 8 + map] = (h16)o;
                }
            }
        }
    }
}

__global__ __launch_bounds__(256) void k_c1(
    const float* __restrict__ x, const float* __restrict__ c1_w,
    const float* __restrict__ c1_b, h16* __restrict__ s2g, int B)
{
    __shared__ __align__(16) h16 s2l[C1_IMG * S2IMGH];   // 25,216 B
    __shared__ float c1w_s[152];
    __shared__ float c1b_s[8];

    const int tid  = threadIdx.x;
    const int ph   = blockIdx.x & 1;
    const int img0 = (blockIdx.x >> 1) * C1_IMG;
    const int nimg = min(C1_IMG, B - img0);
    if (nimg <= 0) return;

    if (tid < 150) c1w_s[tid] = c1_w[tid];
    if (tid < 6)   c1b_s[tid] = c1_b[tid];
    // zero-init s2l (NaN hygiene: ch6/7 + unwritten slots must be finite)
    {
        const half8 z = {(h16)0,(h16)0,(h16)0,(h16)0,(h16)0,(h16)0,(h16)0,(h16)0};
        half8* zp = (half8*)s2l;
        for (int i = tid; i < C1_IMG * 197; i += 256) zp[i] = z;
    }
    __syncthreads();

    const int lane = tid & 63, wv = tid >> 6;
    const int nloc = lane & 15, q4 = lane >> 4;

    // ---- Toeplitz B fragments (round-10/12 proven) ----
    half8 bf[3][5];
    float bias[3];
    #pragma unroll
    for (int t = 0; t < 3; ++t) {
        const int tile = 3 * wv + t;
        const int map  = tile >> 1;
        const int j    = ((tile & 1) << 4) + nloc;
        bias[t] = c1b_s[map];
        #pragma unroll
        for (int ks = 0; ks < 5; ++ks) {
            half8 f;
            #pragma unroll
            for (int jj = 0; jj < 8; ++jj) {
                const int d = q4 * 8 + jj - j;
                f[jj] = (d >= 0 && d < 5) ? (h16)c1w_s[map * 25 + ks * 5 + d] : (h16)0;
            }
            bf[t][ks] = f;
        }
    }

    // ---- A rows: m-row = (img = nloc>>1, half = nloc&1), clamped for tails ----
    const int imgL = nloc >> 1, hf = nloc & 1;
    const int imgC = min(imgL, nimg - 1);
    const float* xg = x + (size_t)(img0 + imgC) * 1024 + hf * (14 * 32) + q4 * 8;

    if (ph == 0) c1_phase<0, 8>(xg, bf, bias, s2l, lane, wv, nloc, q4);
    else         c1_phase<8, 6>(xg, bf, bias, s2l, lane, wv, nloc, q4);
    __syncthreads();

    // ---- flush this phase's chunk set, coalesced ----
    // ph0: ip {0..3, 7..10} -> pos [0,56) u [98,154)   (112 chunks/img)
    // ph1: ip {4..6, 11..13} -> pos [56,98) u [154,196) (84 chunks/img)
    const int nch = ph ? 84 : 112;
    for (int i = tid; i < C1_IMG * nch; i += 256) {
        const int img = i / nch, ii = i % nch;
        const int pos = ph ? (ii < 42 ? 56 + ii : 112 + ii)
                           : (ii < 56 ? ii : 42 + ii);
        if (img < nimg)
            *(half8*)(s2g + (size_t)(img0 + img) * S2IMGH + pos * 8) =
                *(const half8*)(s2l + img * S2IMGH + pos * 8);
    }
}

// ============================ K2: C3 MFMA + tanh + pool, q-split ============================
// grid = 2 * B/16. qs = bx&1 takes positions [13*qs, min(25,13*qs+13)).
__device__ __constant__ int C3_INV[16][6] = {
    {0,1,2,-1,-1,-1},{-1,0,1,2,-1,-1},{-1,-1,0,1,2,-1},{-1,-1,-1,0,1,2},
    {0,-1,-1,-1,1,2},{0,1,-1,-1,-1,2},
    {0,1,2,3,-1,-1},{-1,0,1,2,3,-1},{-1,-1,0,1,2,3},{0,-1,-1,1,2,3},
    {0,1,-1,-1,2,3},{0,1,2,-1,-1,3},{0,1,-1,2,3,-1},{-1,0,1,-1,2,3},
    {0,-1,1,2,-1,3},
    {0,1,2,3,4,5}
};

__global__ __launch_bounds__(256) void k_c3(
    const h16* __restrict__ s2g,
    const float* __restrict__ c3_w3, const float* __restrict__ c3_b3,
    const float* __restrict__ c3_w4, const float* __restrict__ c3_b4,
    const float* __restrict__ c3_w6, const float* __restrict__ c3_b6,
    h16* __restrict__ s4g, int B)
{
    __shared__ __align__(16) h16 s2i[16 * S2IMGH];     // 50,432 B

    const int tid  = threadIdx.x;
    const int qs   = blockIdx.x & 1;
    const int img0 = (blockIdx.x >> 1) * 16;
    const int nimg = min(16, B - img0);
    if (nimg <= 0) return;

    // coalesced staging (zero-fill missing imgs)
    {
        const half8 z = {(h16)0,(h16)0,(h16)0,(h16)0,(h16)0,(h16)0,(h16)0,(h16)0};
        const int img = tid >> 4;
        for (int c = (tid & 15); c < 197; c += 16)
            *(half8*)(s2i + img * S2IMGH + c * 8) =
                (img < nimg) ? *(const half8*)(s2g + (size_t)(img0 + img) * S2IMGH + c * 8)
                             : z;
    }

    const int lane = tid & 63, wv = tid >> 6;
    const int nloc = lane & 15, q4 = lane >> 4;

    // B fragments in registers (round-12 proven mapping)
    half8 bf[7];
    #pragma unroll
    for (int t = 0; t < 7; ++t) {
        half8 f;
        int dr, dc; bool valid = true;
        if (t <= 4)      { dr = q4; dc = t; }
        else if (t == 5) { dr = 4; dc = q4; }
        else             { dr = 4; dc = 4; valid = (q4 == 0); }
        #pragma unroll
        for (int j = 0; j < 8; ++j) {
            float val = 0.0f;
            if (valid && j < 6) {
                const int cc = C3_INV[nloc][j];
                if (cc >= 0) {
                    const int off = dr * 5 + dc;
                    if (nloc < 6)       val = c3_w3[(nloc * 3 + cc) * 25 + off];
                    else if (nloc < 15) val = c3_w4[((nloc - 6) * 4 + cc) * 25 + off];
                    else                val = c3_w6[cc * 25 + off];
                }
            }
            f[j] = (h16)val;
        }
        bf[t] = f;
    }
    const float bias = (nloc < 6) ? c3_b3[nloc]
                     : (nloc < 15) ? c3_b4[nloc - 6] : c3_b6[0];
    __syncthreads();

    {
        const int abase = nloc * S2IMGH;
        const int qlo = qs * 13, qhi = qs ? 25 : 13;
        for (int q = qlo + wv; q < qhi; q += 4) {
            const int pr = q / 5, pc = q % 5;
            f32x4 acc[2][2];
            #pragma unroll
            for (int a = 0; a < 2; ++a)
                #pragma unroll
                for (int b2 = 0; b2 < 2; ++b2)
                    acc[a][b2] = (f32x4){0.f, 0.f, 0.f, 0.f};
            #pragma unroll
            for (int a = 0; a < 2; ++a) {
                #pragma unroll
                for (int b2 = 0; b2 < 2; ++b2) {
                    const int r = 2 * pr + a, col = 2 * pc + b2;
                    #pragma unroll
                    for (int t = 0; t < 5; ++t) {
                        half8 A = *(const half8*)(s2i + abase + ((r + q4) * 14 + col + t) * 8);
                        acc[a][b2] = __builtin_amdgcn_mfma_f32_16x16x32_f16(A, bf[t], acc[a][b2], 0, 0, 0);
                    }
                    half8 A5 = *(const half8*)(s2i + abase + ((r + 4) * 14 + col + q4) * 8);
                    acc[a][b2] = __builtin_amdgcn_mfma_f32_16x16x32_f16(A5, bf[5], acc[a][b2], 0, 0, 0);
                    half8 A6 = *(const half8*)(s2i + abase + ((r + 4) * 14 + col + 4) * 8);
                    acc[a][b2] = __builtin_amdgcn_mfma_f32_16x16x32_f16(A6, bf[6], acc[a][b2], 0, 0, 0);
                }
            }
            const int pos = pr * 5 + pc;
            #pragma unroll
            for (int rr = 0; rr < 4; ++rr) {
                const int img = q4 * 4 + rr;
                if (img < nimg) {
                    float s = fast_tanh(acc[0][0][rr] + bias) + fast_tanh(acc[0][1][rr] + bias)
                            + fast_tanh(acc[1][0][rr] + bias) + fast_tanh(acc[1][1][rr] + bias);
                    s4g[(size_t)(img0 + img) * 400 + nloc * 25 + pos] = (h16)(0.25f * s);
                }
            }
        }
    }
}

// ============================ K3: tail as 3 chained MFMA GEMMs ============================
// (unchanged)
#define KT_IMG   16
#define S4L_STR  424
#define C5O_STR  136
#define F6L_STR  104
#define KT_S4L   0
#define KT_C5OL  (KT_IMG * S4L_STR * 2)
#define KT_F6L   (KT_C5OL + KT_IMG * C5O_STR * 2)
#define KT_BIAS  (KT_F6L + KT_IMG * F6L_STR * 2)
#define KT_SMEM  (KT_BIAS + 240 * 4)

__global__ __launch_bounds__(256) void k_tail(
    const h16* __restrict__ s4g,
    const float* __restrict__ c5_w, const float* __restrict__ c5_b,
    const float* __restrict__ l1_w, const float* __restrict__ l1_b,
    const float* __restrict__ l2_w, const float* __restrict__ l2_b,
    float* __restrict__ out, int B)
{
    __shared__ __align__(16) char smem[KT_SMEM];
    h16*   s4l   = (h16*)(smem + KT_S4L);
    h16*   c5ol  = (h16*)(smem + KT_C5OL);
    h16*   f6l   = (h16*)(smem + KT_F6L);
    float* c5b_s = (float*)(smem + KT_BIAS);
    float* l1b_s = c5b_s + 128;
    float* l2b_s = l1b_s + 96;

    const int tid  = threadIdx.x;
    const int img0 = blockIdx.x * KT_IMG;
    const int nimg = min(KT_IMG, B - img0);
    if (nimg <= 0) return;

    if (tid < 128)      c5b_s[tid] = (tid < 120) ? c5_b[tid] : 0.f;
    else if (tid < 224) { int i = tid - 128; l1b_s[i] = (i < 84) ? l1_b[i] : 0.f; }
    else if (tid < 240) { int i = tid - 224; l2b_s[i] = (i < 10) ? l2_b[i] : 0.f; }

    {
        const half8 z = {(h16)0,(h16)0,(h16)0,(h16)0,(h16)0,(h16)0,(h16)0,(h16)0};
        for (int i = tid; i < KT_IMG * 53; i += 256) {
            int img = i / 53, cc = i % 53;
            half8 v = z;
            if (img < nimg && cc < 50)
                v = *(const half8*)(s4g + (size_t)(img0 + img) * 400 + cc * 8);
            *(half8*)(s4l + img * S4L_STR + cc * 8) = v;
        }
    }
    __syncthreads();

    const int lane = tid & 63, wv = tid >> 6;
    const int nloc = lane & 15, q4 = lane >> 4;
    const half8 z8 = {(h16)0,(h16)0,(h16)0,(h16)0,(h16)0,(h16)0,(h16)0,(h16)0};

    // ===== C5 =====
    {
        const int nb = wv * 2;
        f32x4 acc[2];
        acc[0] = (f32x4){0.f,0.f,0.f,0.f};
        acc[1] = (f32x4){0.f,0.f,0.f,0.f};
        for (int ks = 0; ks < 13; ++ks) {
            const int ka = ks * 32 + q4 * 8;
            half8 A = *(const half8*)(s4l + nloc * S4L_STR + ka);
            #pragma unroll
            for (int t = 0; t < 2; ++t) {
                const int n = (nb + t) * 16 + nloc;
                half8 Bf = z8;
                if (n < 120 && ka < 400) {
                    float4 u0 = *(const float4*)(c5_w + n * 400 + ka);
                    float4 u1 = *(const float4*)(c5_w + n * 400 + ka + 4);
                    Bf = cvt8(u0, u1);
                }
                acc[t] = __builtin_amdgcn_mfma_f32_16x16x32_f16(A, Bf, acc[t], 0, 0, 0);
            }
        }
        #pragma unroll
        for (int t = 0; t < 2; ++t) {
            const int o = (nb + t) * 16 + nloc;
            const float bo = c5b_s[o];
            #pragma unroll
            for (int r = 0; r < 4; ++r) {
                const int img = q4 * 4 + r;
                c5ol[img * C5O_STR + o] = (h16)fast_tanh(acc[t][r] + bo);
            }
        }
    }
    __syncthreads();

    // ===== F6 =====
    if (wv < 3) {
        const int nb = wv * 2;
        f32x4 acc[2];
        acc[0] = (f32x4){0.f,0.f,0.f,0.f};
        acc[1] = (f32x4){0.f,0.f,0.f,0.f};
        for (int ks = 0; ks < 4; ++ks) {
            const int ka = ks * 32 + q4 * 8;
            half8 A = *(const half8*)(c5ol + nloc * C5O_STR + ka);
            #pragma unroll
            for (int t = 0; t < 2; ++t) {
                const int n = (nb + t) * 16 + nloc;
                half8 Bf = z8;
                if (n < 84 && ka < 120) {
                    float4 u0 = *(const float4*)(l1_w + n * 120 + ka);
                    float4 u1 = *(const float4*)(l1_w + n * 120 + ka + 4);
                    Bf = cvt8(u0, u1);
                }
                acc[t] = __builtin_amdgcn_mfma_f32_16x16x32_f16(A, Bf, acc[t], 0, 0, 0);
            }
        }
        #pragma unroll
        for (int t = 0; t < 2; ++t) {
            const int o = (nb + t) * 16 + nloc;
            const float bo = l1b_s[o];
            #pragma unroll
            for (int r = 0; r < 4; ++r) {
                const int img = q4 * 4 + r;
                f6l[img * F6L_STR + o] = (h16)fast_tanh(acc[t][r] + bo);
            }
        }
    }
    __syncthreads();

    // ===== OUT =====
    if (wv == 0) {
        f32x4 acc = (f32x4){0.f,0.f,0.f,0.f};
        #pragma unroll
        for (int ks = 0; ks < 3; ++ks) {
            const int ka = ks * 32 + q4 * 8;
            half8 A = *(const half8*)(f6l + nloc * F6L_STR + ka);
            half8 Bf = z8;
            #pragma unroll
            for (int i = 0; i < 8; ++i) {
                const int k = ka + i;
                if (nloc < 10 && k < 84) Bf[i] = (h16)l2_w[nloc * 84 + k];
            }
            acc = __builtin_amdgcn_mfma_f32_16x16x32_f16(A, Bf, acc, 0, 0, 0);
        }
        if (nloc < 10) {
            #pragma unroll
            for (int r = 0; r < 4; ++r) {
                const int img = q4 * 4 + r;
                if (img < nimg)
                    out[(size_t)(img0 + img) * 10 + nloc] = acc[r] + l2b_s[nloc];
            }
        }
    }
}

extern "C" void kernel_launch(void* const* d_in, const int* in_sizes, int n_in,
                              void* d_out, int out_size, void* d_ws, size_t ws_size,
                              hipStream_t stream) {
    const float* x     = (const float*)d_in[0];
    const float* c1_w  = (const float*)d_in[1];
    const float* c1_b  = (const float*)d_in[2];
    const float* c3_w3 = (const float*)d_in[3];
    const float* c3_b3 = (const float*)d_in[4];
    const float* c3_w4 = (const float*)d_in[5];
    const float* c3_b4 = (const float*)d_in[6];
    const float* c3_w6 = (const float*)d_in[7];
    const float* c3_b6 = (const float*)d_in[8];
    const float* c5_w  = (const float*)d_in[9];
    const float* c5_b  = (const float*)d_in[10];
    const float* l1_w  = (const float*)d_in[11];
    const float* l1_b  = (const float*)d_in[12];
    const float* l2_w  = (const float*)d_in[13];
    const float* l2_b  = (const float*)d_in[14];
    float* out = (float*)d_out;

    const int B = in_sizes[0] / 1024;   // [B,1,32,32]

    // ws: s2 f16 interleaved [B][1576] | s4 f16 [B][400]
    h16* s2g = (h16*)d_ws;
    h16* s4g = (h16*)((char*)d_ws + (size_t)B * S2IMGH * 2);

    k_c1<<<2 * ((B + C1_IMG - 1) / C1_IMG), 256, 0, stream>>>(x, c1_w, c1_b, s2g, B);
    k_c3<<<2 * ((B + 15) / 16), 256, 0, stream>>>(s2g, c3_w3, c3_b3, c3_w4, c3_b4,
                                                  c3_w6, c3_b6, s4g, B);
    k_tail<<<(B + KT_IMG - 1) / KT_IMG, 256, 0, stream>>>(s4g, c5_w, c5_b,
                                                          l1_w, l1_b, l2_w, l2_b, out, B);
}

// Round 14
// 174.936 us; speedup vs baseline: 1.2255x; 1.2255x over previous
//
#include <hip/hip_runtime.h>

typedef float f32x4 __attribute__((ext_vector_type(4)));
typedef _Float16 h16;
typedef h16 half8 __attribute__((ext_vector_type(8)));
typedef h16 half4 __attribute__((ext_vector_type(4)));

__device__ __forceinline__ float fast_tanh(float x) {
    float e = __expf(2.0f * x);
    return fmaf(-2.0f, __builtin_amdgcn_rcpf(e + 1.0f), 1.0f);
}
__device__ __forceinline__ half8 cvt8(float4 u0, float4 u1) {
    return (half8){(h16)u0.x,(h16)u0.y,(h16)u0.z,(h16)u0.w,
                   (h16)u1.x,(h16)u1.y,(h16)u1.z,(h16)u1.w};
}

#define S2IMGH 1576   // s2 halves per image: [196 pos + 1 pad][8 ch]

// ============================ K1: C1 via Toeplitz MFMA ============================
// ROUND-10 VERBATIM (best measured: ~52 us). 8 img/block, grid B/8.
// LDS-staged x, rolling 5-row register window, scattered h16 stores to s2g.
// Rounds 11-13 established every restructuring of this kernel regresses.
#define C1_IMG 8
#define XROW  40
#define XIMGH (32 * XROW + 8)     // 1288 halves

__global__ __launch_bounds__(256) void k_c1(
    const float* __restrict__ x, const float* __restrict__ c1_w,
    const float* __restrict__ c1_b, h16* __restrict__ s2g, int B)
{
    __shared__ __align__(16) h16 xs[C1_IMG * XIMGH];   // 20,608 B
    __shared__ float c1w_s[152];
    __shared__ float c1b_s[8];

    const int tid  = threadIdx.x;
    const int img0 = blockIdx.x * C1_IMG;
    const int nimg = min(C1_IMG, B - img0);
    if (nimg <= 0) return;

    if (tid < 150) c1w_s[tid] = c1_w[tid];
    if (tid < 6)   c1b_s[tid] = c1_b[tid];

    {
        const float4* xg = (const float4*)(x + (size_t)img0 * 1024);
        const int n4 = nimg * 256;
        for (int i = tid; i < n4; i += 256) {
            float4 v = xg[i];
            int img = i >> 8, q = i & 255;
            int row = q >> 3, col4 = (q & 7) << 2;
            *(half4*)(xs + img * XIMGH + row * XROW + col4) =
                (half4){(h16)v.x, (h16)v.y, (h16)v.z, (h16)v.w};
        }
    }
    __syncthreads();

    const int lane = tid & 63, wv = tid >> 6;
    const int nloc = lane & 15, q4 = lane >> 4;

    half8 bf[3][5];
    float bias[3];
    #pragma unroll
    for (int t = 0; t < 3; ++t) {
        const int tile = 3 * wv + t;
        const int map  = tile >> 1;
        const int j    = ((tile & 1) << 4) + nloc;
        bias[t] = c1b_s[map];
        #pragma unroll
        for (int ks = 0; ks < 5; ++ks) {
            half8 f;
            #pragma unroll
            for (int jj = 0; jj < 8; ++jj) {
                const int d = q4 * 8 + jj - j;
                f[jj] = (d >= 0 && d < 5) ? (h16)c1w_s[map * 25 + ks * 5 + d] : (h16)0;
            }
            bf[t][ks] = f;
        }
    }

    const int imgL = nloc >> 1, hf = nloc & 1;
    const h16* xrow = xs + imgL * XIMGH + hf * (14 * XROW) + q4 * 8;
    half8 rf[5];
    #pragma unroll
    for (int r = 0; r < 5; ++r) rf[r] = *(const half8*)(xrow + r * XROW);

    float t0[3][4];
    for (int cr = 0; cr < 14; ++cr) {
        f32x4 acc[3];
        #pragma unroll
        for (int t = 0; t < 3; ++t) acc[t] = (f32x4){0.f, 0.f, 0.f, 0.f};
        #pragma unroll
        for (int ks = 0; ks < 5; ++ks) {
            #pragma unroll
            for (int t = 0; t < 3; ++t)
                acc[t] = __builtin_amdgcn_mfma_f32_16x16x32_f16(rf[ks], bf[t][ks], acc[t], 0, 0, 0);
        }
        if ((cr & 1) == 0) {
            #pragma unroll
            for (int t = 0; t < 3; ++t)
                #pragma unroll
                for (int r = 0; r < 4; ++r)
                    t0[t][r] = fast_tanh(acc[t][r] + bias[t]);
        } else {
            #pragma unroll
            for (int t = 0; t < 3; ++t) {
                const int tile = 3 * wv + t;
                const int jp   = (((tile & 1) << 4) + nloc) >> 1;
                const int map  = tile >> 1;
                #pragma unroll
                for (int r = 0; r < 4; ++r) {
                    float s = t0[t][r] + fast_tanh(acc[t][r] + bias[t]);
                    float o = 0.25f * (s + __shfl_xor(s, 1));
                    const int m = q4 * 4 + r;                 // C/D row = m
                    const int img = m >> 1, mh = m & 1;
                    const int ip  = (cr >> 1) + 7 * mh;
                    if (!(lane & 1) && jp < 14 && img < nimg)
                        s2g[(size_t)(img0 + img) * S2IMGH + (ip * 14 + jp) * 8 + map] = (h16)o;
                }
            }
        }
        if (cr < 13) {
            rf[0] = rf[1]; rf[1] = rf[2]; rf[2] = rf[3]; rf[3] = rf[4];
            rf[4] = *(const half8*)(xrow + (cr + 5) * XROW);
        }
    }
}

// ============================ K2: merged C3 + C5 + F6 + OUT ============================
// 16 img/block, grid B/16. C3 MFMA (round-12 register-B variant) holds pooled
// results in registers across a barrier, then scatters into s4l which ALIASES
// the dead s2i region; tail GEMMs (round-9 proven) run in the same block.
// LDS = 50,432 (s2i / aliased tail bufs) + 960 (biases) = 51,392 B -> 3 blk/CU.
#define S4L_STR  424
#define C5O_STR  136
#define F6L_STR  104
#define AL_C5O   (16 * S4L_STR)              // h16 offsets inside alias region
#define AL_F6    (AL_C5O + 16 * C5O_STR)
#define ALIAS_H  (AL_F6 + 16 * F6L_STR)      // 10,112 h16 = 20,224 B < 50,432 ✓

__device__ __constant__ int C3_INV[16][6] = {
    {0,1,2,-1,-1,-1},{-1,0,1,2,-1,-1},{-1,-1,0,1,2,-1},{-1,-1,-1,0,1,2},
    {0,-1,-1,-1,1,2},{0,1,-1,-1,-1,2},
    {0,1,2,3,-1,-1},{-1,0,1,2,3,-1},{-1,-1,0,1,2,3},{0,-1,-1,1,2,3},
    {0,1,-1,-1,2,3},{0,1,2,-1,-1,3},{0,1,-1,2,3,-1},{-1,0,1,-1,2,3},
    {0,-1,1,2,-1,3},
    {0,1,2,3,4,5}
};

__global__ __launch_bounds__(256) void k_c3t(
    const h16* __restrict__ s2g,
    const float* __restrict__ c3_w3, const float* __restrict__ c3_b3,
    const float* __restrict__ c3_w4, const float* __restrict__ c3_b4,
    const float* __restrict__ c3_w6, const float* __restrict__ c3_b6,
    const float* __restrict__ c5_w, const float* __restrict__ c5_b,
    const float* __restrict__ l1_w, const float* __restrict__ l1_b,
    const float* __restrict__ l2_w, const float* __restrict__ l2_b,
    float* __restrict__ out, int B)
{
    __shared__ __align__(16) h16 s2i[16 * S2IMGH];     // 50,432 B (aliased later)
    __shared__ float c5b_s[128];
    __shared__ float l1b_s[96];
    __shared__ float l2b_s[16];
    h16* s4l  = s2i;            // alias: valid only after the post-C3 barrier
    h16* c5ol = s2i + AL_C5O;
    h16* f6l  = s2i + AL_F6;

    const int tid  = threadIdx.x;
    const int img0 = blockIdx.x * 16;
    const int nimg = min(16, B - img0);
    if (nimg <= 0) return;

    if (tid < 128)      c5b_s[tid] = (tid < 120) ? c5_b[tid] : 0.f;
    else if (tid < 224) { int i = tid - 128; l1b_s[i] = (i < 84) ? l1_b[i] : 0.f; }
    else if (tid < 240) { int i = tid - 224; l2b_s[i] = (i < 10) ? l2_b[i] : 0.f; }

    // ---- stage s2 coalesced (zero-fill missing imgs) ----
    {
        const half8 z = {(h16)0,(h16)0,(h16)0,(h16)0,(h16)0,(h16)0,(h16)0,(h16)0};
        const int img = tid >> 4;
        for (int c = (tid & 15); c < 197; c += 16)
            *(half8*)(s2i + img * S2IMGH + c * 8) =
                (img < nimg) ? *(const half8*)(s2g + (size_t)(img0 + img) * S2IMGH + c * 8)
                             : z;
    }

    const int lane = tid & 63, wv = tid >> 6;
    const int nloc = lane & 15, q4 = lane >> 4;
    const half8 z8 = {(h16)0,(h16)0,(h16)0,(h16)0,(h16)0,(h16)0,(h16)0,(h16)0};

    // ---- C3 B fragments in registers (round-12 proven mapping) ----
    half8 bf[7];
    #pragma unroll
    for (int t = 0; t < 7; ++t) {
        half8 f;
        int dr, dc; bool valid = true;
        if (t <= 4)      { dr = q4; dc = t; }
        else if (t == 5) { dr = 4; dc = q4; }
        else             { dr = 4; dc = 4; valid = (q4 == 0); }
        #pragma unroll
        for (int j = 0; j < 8; ++j) {
            float val = 0.0f;
            if (valid && j < 6) {
                const int cc = C3_INV[nloc][j];
                if (cc >= 0) {
                    const int off = dr * 5 + dc;
                    if (nloc < 6)       val = c3_w3[(nloc * 3 + cc) * 25 + off];
                    else if (nloc < 15) val = c3_w4[((nloc - 6) * 4 + cc) * 25 + off];
                    else                val = c3_w6[cc * 25 + off];
                }
            }
            f[j] = (h16)val;
        }
        bf[t] = f;
    }
    const float c3bias = (nloc < 6) ? c3_b3[nloc]
                       : (nloc < 15) ? c3_b4[nloc - 6] : c3_b6[0];
    __syncthreads();

    // ---- C3 MFMA phase (round-9/10 proven), results held in registers ----
    float res[7][4];
    int nq = 0;
    {
        const int abase = nloc * S2IMGH;
        for (int q = wv; q < 25; q += 4, ++nq) {
            const int pr = q / 5, pc = q % 5;
            f32x4 acc[2][2];
            #pragma unroll
            for (int a = 0; a < 2; ++a)
                #pragma unroll
                for (int b2 = 0; b2 < 2; ++b2)
                    acc[a][b2] = (f32x4){0.f, 0.f, 0.f, 0.f};
            #pragma unroll
            for (int a = 0; a < 2; ++a) {
                #pragma unroll
                for (int b2 = 0; b2 < 2; ++b2) {
                    const int r = 2 * pr + a, col = 2 * pc + b2;
                    #pragma unroll
                    for (int t = 0; t < 5; ++t) {
                        half8 A = *(const half8*)(s2i + abase + ((r + q4) * 14 + col + t) * 8);
                        acc[a][b2] = __builtin_amdgcn_mfma_f32_16x16x32_f16(A, bf[t], acc[a][b2], 0, 0, 0);
                    }
                    half8 A5 = *(const half8*)(s2i + abase + ((r + 4) * 14 + col + q4) * 8);
                    acc[a][b2] = __builtin_amdgcn_mfma_f32_16x16x32_f16(A5, bf[5], acc[a][b2], 0, 0, 0);
                    half8 A6 = *(const half8*)(s2i + abase + ((r + 4) * 14 + col + 4) * 8);
                    acc[a][b2] = __builtin_amdgcn_mfma_f32_16x16x32_f16(A6, bf[6], acc[a][b2], 0, 0, 0);
                }
            }
            #pragma unroll
            for (int rr = 0; rr < 4; ++rr) {
                float s = fast_tanh(acc[0][0][rr] + c3bias) + fast_tanh(acc[0][1][rr] + c3bias)
                        + fast_tanh(acc[1][0][rr] + c3bias) + fast_tanh(acc[1][1][rr] + c3bias);
                res[nq][rr] = 0.25f * s;
            }
        }
    }
    __syncthreads();   // ALL s2i reads complete — alias region now writable

    // ---- zero s4l (cols 400..423 must be 0 for C5 K-padding) ----
    {
        half8* zp = (half8*)s4l;
        for (int i = tid; i < (16 * S4L_STR) / 8; i += 256) zp[i] = z8;
    }
    __syncthreads();

    // ---- scatter held C3 results into s4l [img][nloc*25+pos] ----
    {
        int iq = 0;
        for (int q = wv; q < 25; q += 4, ++iq) {
            #pragma unroll
            for (int rr = 0; rr < 4; ++rr) {
                const int img = q4 * 4 + rr;
                s4l[img * S4L_STR + nloc * 25 + q] = (h16)res[iq][rr];
            }
        }
    }
    __syncthreads();

    // ===== C5: M16 N128(120) K416(400)  (round-9 proven) =====
    {
        const int nb = wv * 2;
        f32x4 acc[2];
        acc[0] = (f32x4){0.f,0.f,0.f,0.f};
        acc[1] = (f32x4){0.f,0.f,0.f,0.f};
        for (int ks = 0; ks < 13; ++ks) {
            const int ka = ks * 32 + q4 * 8;
            half8 A = *(const half8*)(s4l + nloc * S4L_STR + ka);
            #pragma unroll
            for (int t = 0; t < 2; ++t) {
                const int n = (nb + t) * 16 + nloc;
                half8 Bf = z8;
                if (n < 120 && ka < 400) {
                    float4 u0 = *(const float4*)(c5_w + n * 400 + ka);
                    float4 u1 = *(const float4*)(c5_w + n * 400 + ka + 4);
                    Bf = cvt8(u0, u1);
                }
                acc[t] = __builtin_amdgcn_mfma_f32_16x16x32_f16(A, Bf, acc[t], 0, 0, 0);
            }
        }
        #pragma unroll
        for (int t = 0; t < 2; ++t) {
            const int o = (nb + t) * 16 + nloc;
            const float bo = c5b_s[o];
            #pragma unroll
            for (int r = 0; r < 4; ++r) {
                const int img = q4 * 4 + r;
                c5ol[img * C5O_STR + o] = (h16)fast_tanh(acc[t][r] + bo);
            }
        }
    }
    __syncthreads();

    // ===== F6: M16 N96(84) K128(120) =====
    if (wv < 3) {
        const int nb = wv * 2;
        f32x4 acc[2];
        acc[0] = (f32x4){0.f,0.f,0.f,0.f};
        acc[1] = (f32x4){0.f,0.f,0.f,0.f};
        for (int ks = 0; ks < 4; ++ks) {
            const int ka = ks * 32 + q4 * 8;
            half8 A = *(const half8*)(c5ol + nloc * C5O_STR + ka);
            #pragma unroll
            for (int t = 0; t < 2; ++t) {
                const int n = (nb + t) * 16 + nloc;
                half8 Bf = z8;
                if (n < 84 && ka < 120) {
                    float4 u0 = *(const float4*)(l1_w + n * 120 + ka);
                    float4 u1 = *(const float4*)(l1_w + n * 120 + ka + 4);
                    Bf = cvt8(u0, u1);
                }
                acc[t] = __builtin_amdgcn_mfma_f32_16x16x32_f16(A, Bf, acc[t], 0, 0, 0);
            }
        }
        #pragma unroll
        for (int t = 0; t < 2; ++t) {
            const int o = (nb + t) * 16 + nloc;
            const float bo = l1b_s[o];
            #pragma unroll
            for (int r = 0; r < 4; ++r) {
                const int img = q4 * 4 + r;
                f6l[img * F6L_STR + o] = (h16)fast_tanh(acc[t][r] + bo);
            }
        }
    }
    __syncthreads();

    // ===== OUT: M16 N16(10) K96(84) =====
    if (wv == 0) {
        f32x4 acc = (f32x4){0.f,0.f,0.f,0.f};
        #pragma unroll
        for (int ks = 0; ks < 3; ++ks) {
            const int ka = ks * 32 + q4 * 8;
            half8 A = *(const half8*)(f6l + nloc * F6L_STR + ka);
            half8 Bf = z8;
            #pragma unroll
            for (int i = 0; i < 8; ++i) {
                const int k = ka + i;
                if (nloc < 10 && k < 84) Bf[i] = (h16)l2_w[nloc * 84 + k];
            }
            acc = __builtin_amdgcn_mfma_f32_16x16x32_f16(A, Bf, acc, 0, 0, 0);
        }
        if (nloc < 10) {
            #pragma unroll
            for (int r = 0; r < 4; ++r) {
                const int img = q4 * 4 + r;
                if (img < nimg)
                    out[(size_t)(img0 + img) * 10 + nloc] = acc[r] + l2b_s[nloc];
            }
        }
    }
}

extern "C" void kernel_launch(void* const* d_in, const int* in_sizes, int n_in,
                              void* d_out, int out_size, void* d_ws, size_t ws_size,
                              hipStream_t stream) {
    const float* x     = (const float*)d_in[0];
    const float* c1_w  = (const float*)d_in[1];
    const float* c1_b  = (const float*)d_in[2];
    const float* c3_w3 = (const float*)d_in[3];
    const float* c3_b3 = (const float*)d_in[4];
    const float* c3_w4 = (const float*)d_in[5];
    const float* c3_b4 = (const float*)d_in[6];
    const float* c3_w6 = (const float*)d_in[7];
    const float* c3_b6 = (const float*)d_in[8];
    const float* c5_w  = (const float*)d_in[9];
    const float* c5_b  = (const float*)d_in[10];
    const float* l1_w  = (const float*)d_in[11];
    const float* l1_b  = (const float*)d_in[12];
    const float* l2_w  = (const float*)d_in[13];
    const float* l2_b  = (const float*)d_in[14];
    float* out = (float*)d_out;

    const int B = in_sizes[0] / 1024;   // [B,1,32,32]

    // ws: s2 f16 interleaved [B][1576]
    h16* s2g = (h16*)d_ws;

    k_c1<<<(B + C1_IMG - 1) / C1_IMG, 256, 0, stream>>>(x, c1_w, c1_b, s2g, B);
    k_c3t<<<(B + 15) / 16, 256, 0, stream>>>(s2g, c3_w3, c3_b3, c3_w4, c3_b4,
                                             c3_w6, c3_b6, c5_w, c5_b,
                                             l1_w, l1_b, l2_w, l2_b, out, B);
}